// Round 7
// baseline (382.176 us; speedup 1.0000x reference)
//
#include <hip/hip_runtime.h>
#include <hip/hip_bf16.h>
#include <hip/hip_fp16.h>
#include <cstdint>
#include <cstddef>

#define BB 32
#define NN 256
#define MM 256
#define DD 512
#define NEGF (-1e9f)
#define LOG2E 1.4426950408889634f
#define WARR 131328  // 513*256 floats: one (batch, diag-array) plane

typedef __fp16 h2 __attribute__((ext_vector_type(2)));

__device__ __forceinline__ uint32_t pack_q(float a, float b) {
  h2 r = __builtin_amdgcn_cvt_pkrtz(a, b);      // (q1,q3) -> 2x fp16
  return __builtin_bit_cast(uint32_t, r);
}
__device__ __forceinline__ float2 unpack_q(uint32_t u) {
  h2 r = __builtin_bit_cast(h2, u);
  return make_float2((float)r.x, (float)r.y);
}

__device__ __forceinline__ float softplus_f(float x) {
  return fmaxf(x, 0.f) + __logf(1.f + __expf(-fabsf(x)));
}
__device__ __forceinline__ float logsig_f(float x) {
  return fminf(x, 0.f) - __logf(1.f + __expf(-fabsf(x)));
}

// ---------------- GEMM + activation + diag-layout side store ----------------
template<int OP>
__global__ __launch_bounds__(256) void gemm_act(const float* __restrict__ X,
                                                const float* __restrict__ Y,
                                                float* __restrict__ out,
                                                float* __restrict__ diag) {
  const int b  = blockIdx.z;
  const int m0 = blockIdx.y * 64;
  const int n0 = blockIdx.x * 64;
  const float* Xb = X + (size_t)b * NN * DD;
  const float* Yb = Y + (size_t)b * MM * DD;
  float* diagb = diag + (size_t)b * WARR;

  __shared__ float xs[16][68];
  __shared__ float ys[16][68];

  const int t  = threadIdx.x;
  const int tm = t >> 4;
  const int tn = t & 15;
  const int lr = t >> 2;
  const int lk = (t & 3) << 2;

  float acc[4][4];
  #pragma unroll
  for (int a = 0; a < 4; ++a)
    #pragma unroll
    for (int c = 0; c < 4; ++c) acc[a][c] = 0.f;

  for (int k0 = 0; k0 < DD; k0 += 16) {
    float4 xv = *(const float4*)(Xb + (size_t)(m0 + lr) * DD + k0 + lk);
    float4 yv = *(const float4*)(Yb + (size_t)(n0 + lr) * DD + k0 + lk);
    __syncthreads();
    xs[lk + 0][lr] = xv.x; xs[lk + 1][lr] = xv.y;
    xs[lk + 2][lr] = xv.z; xs[lk + 3][lr] = xv.w;
    ys[lk + 0][lr] = yv.x; ys[lk + 1][lr] = yv.y;
    ys[lk + 2][lr] = yv.z; ys[lk + 3][lr] = yv.w;
    __syncthreads();
    #pragma unroll
    for (int kk = 0; kk < 16; ++kk) {
      float4 xr = *(const float4*)&xs[kk][tm << 2];
      float4 yr = *(const float4*)&ys[kk][tn << 2];
      float xa[4] = {xr.x, xr.y, xr.z, xr.w};
      float ya[4] = {yr.x, yr.y, yr.z, yr.w};
      #pragma unroll
      for (int a = 0; a < 4; ++a)
        #pragma unroll
        for (int c = 0; c < 4; ++c)
          acc[a][c] = fmaf(xa[a], ya[c], acc[a][c]);
    }
  }

  #pragma unroll
  for (int a = 0; a < 4; ++a) {
    const int row = m0 + (tm << 2) + a;
    float4 o;
    float* po = (float*)&o;
    #pragma unroll
    for (int c = 0; c < 4; ++c) {
      const float v = acc[a][c];
      const float act = (OP == 0) ? softplus_f(v) : logsig_f(v);
      po[c] = act;
      const int col = n0 + (tn << 2) + c;
      diagb[(size_t)(row + col + 2) * 256 + row] = act * LOG2E;  // base-2 domain
    }
    *(float4*)(out + (size_t)b * NN * MM + (size_t)row * MM + n0 + (tn << 2)) = o;
  }
}

// ---------------- wave-synchronous soft-NW fwd+bwd, depth-8 pipeline --------
// One 64-lane wave per batch; lane t owns grid rows 4t+1..4t+4.
// __launch_bounds__(64, 1): only 32 waves run on 256 CUs, so occupancy is
// irrelevant — give the allocator the full VGPR budget so the depth-8
// prefetch ring (thb/ab = 64 VGPRs, qr = 32) stays in registers and loads
// keep their 8-step program-order lead. (Default budget was 56 VGPRs ->
// loads got sunk next to uses -> full L2/L3 latency every step.)
__global__ __launch_bounds__(64, 1) void nw_wave(const float* __restrict__ thD,
                                                 const float* __restrict__ aD,
                                                 uint4* __restrict__ qpD,
                                                 float* __restrict__ aln) {
  const int b = blockIdx.x;
  const int t = threadIdx.x;  // 0..63
  const float4* th4 = (const float4*)(thD + (size_t)b * WARR);
  const float4* a4  = (const float4*)(aD  + (size_t)b * WARR);
  uint4* qp = qpD + (size_t)b * (513 * 64);
  float* ALN = aln + (size_t)b * NN * MM;
  const int i0 = 4 * t + 1;

  // ---------- forward ----------
  float vp[4], vp2[4];
  #pragma unroll
  for (int k = 0; k < 4; ++k) { vp[k] = NEGF; vp2[k] = NEGF; }

  float4 thb[8], ab[8];
  #pragma unroll
  for (int dd = 2; dd <= 9; ++dd) {
    thb[dd & 7] = th4[dd * 64 + t];
    ab[dd & 7]  = a4[dd * 64 + t];
  }

  for (int blk = 0; blk < 64; ++blk) {
    #pragma unroll
    for (int u = 0; u < 8; ++u) {
      const int d  = 2 + blk * 8 + u;      // 2..513 (513 fully masked)
      const int sl = (2 + u) & 7;          // compile-time slot: d & 7

      float vu_in = __shfl_up(vp[3], 1);
      float vd_in = __shfl_up(vp2[3], 1);
      if (t == 0) { vu_in = NEGF; vd_in = (d == 2) ? 0.f : NEGF; }

      const float4 thc = thb[sl];
      const float4 ac  = ab[sl];
      float vnew[4];
      uint32_t pk[4];
      #pragma unroll
      for (int k = 0; k < 4; ++k) {
        const int i = i0 + k;
        const float vu = (k == 0) ? vu_in : vp[k - 1];   // V[i-1][j]
        const float vd = (k == 0) ? vd_in : vp2[k - 1];  // V[i-1][j-1]
        const float vl = vp[k];                          // V[i][j-1]
        const float a  = ((const float*)&ac)[k];
        const float th = ((const float*)&thc)[k];
        const float x0 = a + vu;
        const float x2 = a + vl;
        const float mx = fmaxf(fmaxf(x0, vd), x2);
        const float e0 = __builtin_amdgcn_exp2f(x0 - mx);
        const float e1 = __builtin_amdgcn_exp2f(vd - mx);
        const float e2 = __builtin_amdgcn_exp2f(x2 - mx);
        const float Z  = e0 + e1 + e2;
        const float rz = __builtin_amdgcn_rcpf(Z);
        const float v  = th + mx + __builtin_amdgcn_logf(Z);
        const bool valid = (i <= d - 1) && (i >= d - 256);
        vnew[k] = valid ? v : NEGF;
        pk[k] = pack_q(e0 * rz, e2 * rz);  // (q1, q3); q2 = 1-q1-q3
      }
      if (d <= 512) qp[d * 64 + t] = make_uint4(pk[0], pk[1], pk[2], pk[3]);
      #pragma unroll
      for (int k = 0; k < 4; ++k) { vp2[k] = vp[k]; vp[k] = vnew[k]; }
      if (d + 8 <= 512) {                  // refill same slot, 8 diags ahead
        thb[sl] = th4[(d + 8) * 64 + t];
        ab[sl]  = a4[(d + 8) * 64 + t];
      }
    }
  }

  // ---------- backward: E[i,j] = sum over consumers Q_c * E_c ----------
  float ep[4], ep2[4];
  #pragma unroll
  for (int k = 0; k < 4; ++k) { ep[k] = 0.f; ep2[k] = 0.f; }

  uint4 qr[8];
  #pragma unroll
  for (int x = 0; x < 8; ++x) qr[x] = make_uint4(0, 0, 0, 0);
  #pragma unroll
  for (int dd = 509; dd <= 512; ++dd) qr[dd & 7] = qp[dd * 64 + t];

  for (int blk = 0; blk < 64; ++blk) {
    #pragma unroll
    for (int u = 0; u < 8; ++u) {
      const int s   = 513 - (blk * 8 + u);  // 513..2 (513 fully masked)
      const int slA = (514 - u) & 7;        // slot of diag s+1
      const int slB = (515 - u) & 7;        // slot of diag s+2
      const int slL = (508 - u) & 7;        // slot of diag s-5 (load target)

      const float sh_e1 = __shfl_down(ep[0], 1);
      const float sh_e2 = __shfl_down(ep2[0], 1);
      const uint4 qA = qr[slA];
      const uint4 qB = qr[slB];
      const uint32_t sh_qA = (uint32_t)__shfl_down((int)qA.x, 1);
      const uint32_t sh_qB = (uint32_t)__shfl_down((int)qB.x, 1);

      float enew[4];
      #pragma unroll
      for (int k = 0; k < 4; ++k) {
        const int i = i0 + k;
        const int j = s - i;
        const bool cellv = (j >= 1) && (j <= 256);
        const uint32_t quA = (k < 3) ? (&qA.x)[k + 1] : sh_qA;  // Q(s+1), row i+1
        const uint32_t quB = (k < 3) ? (&qB.x)[k + 1] : sh_qB;  // Q(s+2), row i+1
        const uint32_t qcA = (&qA.x)[k];                        // Q(s+1), row i
        const float2 fA = unpack_q(quA);  // q1 of (i+1, j)
        const float2 fB = unpack_q(quB);  // (q1,q3) of (i+1, j+1)
        const float2 fC = unpack_q(qcA);  // q3 of (i, j+1)
        float q1u = fA.x;
        float q2d = 1.f - fB.x - fB.y;
        float q3l = fC.y;
        const float eu = (k < 3) ? ep[k + 1]  : sh_e1;
        const float ed = (k < 3) ? ep2[k + 1] : sh_e2;
        const float el = ep[k];
        q1u = (i <= 255)             ? q1u : 0.f;
        q2d = (i <= 255 && j <= 255) ? q2d : 0.f;
        q3l = (j <= 255)             ? q3l : 0.f;
        float E = q1u * eu + q2d * ed + q3l * el;
        if (s == 512 && i == 256) E = 1.f;   // terminal seed
        E = cellv ? E : 0.f;
        enew[k] = E;
        if (cellv) ALN[(size_t)(i - 1) * MM + (j - 1)] = E;
      }
      #pragma unroll
      for (int k = 0; k < 4; ++k) { ep2[k] = ep[k]; ep[k] = enew[k]; }
      if (s - 5 >= 2) qr[slL] = qp[(s - 5) * 64 + t];
    }
  }
}

// ---------------- launcher ----------------
extern "C" void kernel_launch(void* const* d_in, const int* in_sizes, int n_in,
                              void* d_out, int out_size, void* d_ws, size_t ws_size,
                              hipStream_t stream) {
  const float* zx = (const float*)d_in[0];
  const float* zy = (const float*)d_in[1];
  const float* gx = (const float*)d_in[2];
  const float* gy = (const float*)d_in[3];

  float* out   = (float*)d_out;
  float* aln   = out;                              // [B][N][M]
  float* theta = out + (size_t)BB * NN * MM;       // [B][N][M]
  float* Amat  = out + (size_t)2 * BB * NN * MM;   // [B][N][M]

  float* ws  = (float*)d_ws;
  float* thD = ws;                                 // [B][513][256] f32
  float* aD  = ws + (size_t)BB * WARR;             // [B][513][256] f32
  uint4* qpD = (uint4*)(ws + (size_t)2 * BB * WARR);  // [B][513][64] uint4 (half2 x4)

  dim3 gg(MM / 64, NN / 64, BB);
  gemm_act<0><<<gg, 256, 0, stream>>>(zx, zy, theta, thD);
  gemm_act<1><<<gg, 256, 0, stream>>>(gx, gy, Amat, aD);
  nw_wave<<<BB, 64, 0, stream>>>(thD, aD, qpD, aln);
}

// Round 11
// 330.595 us; speedup vs baseline: 1.1560x; 1.1560x over previous
//
#include <hip/hip_runtime.h>
#include <hip/hip_bf16.h>
#include <hip/hip_fp16.h>
#include <cstdint>
#include <cstddef>

#define BB 32
#define NN 256
#define MM 256
#define DD 512
#define NEGF (-1e9f)
#define LOG2E 1.4426950408889634f
#define WARR 131328   // 513*256 floats: one (batch, diag-array) plane
#define EPLN 131584   // 514*256 floats: E diag-layout plane

typedef __fp16 h2 __attribute__((ext_vector_type(2)));
typedef float f32x4_t __attribute__((ext_vector_type(4)));
typedef unsigned int u32x4_t __attribute__((ext_vector_type(4)));

__device__ __forceinline__ uint32_t pack_q(float a, float b) {
  h2 r = __builtin_amdgcn_cvt_pkrtz(a, b);
  return __builtin_bit_cast(uint32_t, r);
}
__device__ __forceinline__ float2 unpack_q(uint32_t u) {
  h2 r = __builtin_bit_cast(h2, u);
  return make_float2((float)r.x, (float)r.y);
}
__device__ __forceinline__ float softplus_f(float x) {
  return fmaxf(x, 0.f) + __logf(1.f + __expf(-fabsf(x)));
}
__device__ __forceinline__ float logsig_f(float x) {
  return fminf(x, 0.f) - __logf(1.f + __expf(-fabsf(x)));
}

// drain ALL outstanding vmem (incl. global_load_lds DMA) + lds ops; memory
// clobber + sched_barrier pin every memory op and register consumer.
#define DRAIN() do { \
  asm volatile("s_waitcnt vmcnt(0) lgkmcnt(0)" ::: "memory"); \
  __builtin_amdgcn_sched_barrier(0); \
} while (0)

// ---------------- GEMM + activation + diag-layout side store ----------------
template<int OP>
__global__ __launch_bounds__(256) void gemm_act(const float* __restrict__ X,
                                                const float* __restrict__ Y,
                                                float* __restrict__ out,
                                                float* __restrict__ diag) {
  const int b  = blockIdx.z;
  const int m0 = blockIdx.y * 64;
  const int n0 = blockIdx.x * 64;
  const float* Xb = X + (size_t)b * NN * DD;
  const float* Yb = Y + (size_t)b * MM * DD;
  float* diagb = diag + (size_t)b * WARR;

  __shared__ float xs[16][68];
  __shared__ float ys[16][68];

  const int t  = threadIdx.x;
  const int tm = t >> 4;
  const int tn = t & 15;
  const int lr = t >> 2;
  const int lk = (t & 3) << 2;

  float acc[4][4];
  #pragma unroll
  for (int a = 0; a < 4; ++a)
    #pragma unroll
    for (int c = 0; c < 4; ++c) acc[a][c] = 0.f;

  for (int k0 = 0; k0 < DD; k0 += 16) {
    float4 xv = *(const float4*)(Xb + (size_t)(m0 + lr) * DD + k0 + lk);
    float4 yv = *(const float4*)(Yb + (size_t)(n0 + lr) * DD + k0 + lk);
    __syncthreads();
    xs[lk + 0][lr] = xv.x; xs[lk + 1][lr] = xv.y;
    xs[lk + 2][lr] = xv.z; xs[lk + 3][lr] = xv.w;
    ys[lk + 0][lr] = yv.x; ys[lk + 1][lr] = yv.y;
    ys[lk + 2][lr] = yv.z; ys[lk + 3][lr] = yv.w;
    __syncthreads();
    #pragma unroll
    for (int kk = 0; kk < 16; ++kk) {
      float4 xr = *(const float4*)&xs[kk][tm << 2];
      float4 yr = *(const float4*)&ys[kk][tn << 2];
      float xa[4] = {xr.x, xr.y, xr.z, xr.w};
      float ya[4] = {yr.x, yr.y, yr.z, yr.w};
      #pragma unroll
      for (int a = 0; a < 4; ++a)
        #pragma unroll
        for (int c = 0; c < 4; ++c)
          acc[a][c] = fmaf(xa[a], ya[c], acc[a][c]);
    }
  }

  #pragma unroll
  for (int a = 0; a < 4; ++a) {
    const int row = m0 + (tm << 2) + a;
    float4 o;
    float* po = (float*)&o;
    #pragma unroll
    for (int c = 0; c < 4; ++c) {
      const float v = acc[a][c];
      const float act = (OP == 0) ? softplus_f(v) : logsig_f(v);
      po[c] = act;
      const int col = n0 + (tn << 2) + c;
      diagb[(size_t)(row + col + 2) * 256 + row] = act * LOG2E;  // base-2 domain
    }
    *(float4*)(out + (size_t)b * NN * MM + (size_t)row * MM + n0 + (tn << 2)) = o;
  }
}

// ---------------- DP step helpers ----------------
__device__ __forceinline__ u32x4_t fstep(int d, int t, int i0,
                                         const f32x4_t thc, const f32x4_t ac,
                                         float vp[4], float vp2[4]) {
  float vu_in = __shfl_up(vp[3], 1);
  float vd_in = __shfl_up(vp2[3], 1);
  if (t == 0) { vu_in = NEGF; vd_in = (d == 2) ? 0.f : NEGF; }
  float vnew[4];
  u32x4_t pkv;
  #pragma unroll
  for (int k = 0; k < 4; ++k) {
    const int i = i0 + k;
    const float vu = (k == 0) ? vu_in : vp[k - 1];
    const float vd = (k == 0) ? vd_in : vp2[k - 1];
    const float vl = vp[k];
    const float a  = ac[k];
    const float th = thc[k];
    const float x0 = a + vu;
    const float x2 = a + vl;
    const float mx = fmaxf(fmaxf(x0, vd), x2);
    const float e0 = __builtin_amdgcn_exp2f(x0 - mx);
    const float e1 = __builtin_amdgcn_exp2f(vd - mx);
    const float e2 = __builtin_amdgcn_exp2f(x2 - mx);
    const float Z  = e0 + e1 + e2;
    const float rz = __builtin_amdgcn_rcpf(Z);
    const float v  = th + mx + __builtin_amdgcn_logf(Z);  // log2
    const bool valid = (i <= d - 1) && (i >= d - 256);
    vnew[k] = valid ? v : NEGF;
    pkv[k] = pack_q(e0 * rz, e2 * rz);   // (q1, q3); q2 = 1-q1-q3
  }
  #pragma unroll
  for (int k = 0; k < 4; ++k) { vp2[k] = vp[k]; vp[k] = vnew[k]; }
  return pkv;
}

__device__ __forceinline__ f32x4_t bcompute(int s, int t, int i0,
                                            u32x4_t qA, u32x4_t qB,
                                            const float ep[4], const float ep2[4]) {
  const float sh_e1 = __shfl_down(ep[0], 1);
  const float sh_e2 = __shfl_down(ep2[0], 1);
  const uint32_t sh_qA = (uint32_t)__shfl_down((int)qA.x, 1);
  const uint32_t sh_qB = (uint32_t)__shfl_down((int)qB.x, 1);
  f32x4_t en;
  #pragma unroll
  for (int k = 0; k < 4; ++k) {
    const int i = i0 + k;
    const int j = s - i;
    const bool cellv = (j >= 1) && (j <= 256);
    const uint32_t quA = (k < 3) ? qA[k + 1] : sh_qA;  // Q(s+1), row i+1
    const uint32_t quB = (k < 3) ? qB[k + 1] : sh_qB;  // Q(s+2), row i+1
    const uint32_t qcA = qA[k];                        // Q(s+1), row i
    const float2 fA = unpack_q(quA);
    const float2 fB = unpack_q(quB);
    const float2 fC = unpack_q(qcA);
    float q1u = fA.x;
    float q2d = 1.f - fB.x - fB.y;
    float q3l = fC.y;
    const float eu = (k < 3) ? ep[k + 1]  : sh_e1;
    const float ed = (k < 3) ? ep2[k + 1] : sh_e2;
    const float el = ep[k];
    q1u = (i <= 255)             ? q1u : 0.f;
    q2d = (i <= 255 && j <= 255) ? q2d : 0.f;
    q3l = (j <= 255)             ? q3l : 0.f;
    float E = q1u * eu + q2d * ed + q3l * el;
    if (s == 512 && i == 256) E = 1.f;  // terminal seed
    en[k] = cellv ? E : 0.f;
  }
  return en;
}

// -------- wave-synchronous soft-NW; LDS-staged via global_load_lds ---------
// One 64-lane wave per batch. All global->LDS staging is register-free DMA
// (no async-VGPR hazards); stores are normal C++ stores; drains are
// vmcnt(0)+lgkmcnt(0) at bank boundaries so correctness is independent of
// compiler scheduling/regalloc.
__global__ __launch_bounds__(64, 1) void nw_wave(const float* __restrict__ thD,
                                                 const float* __restrict__ aD,
                                                 u32x4_t* __restrict__ qpD,
                                                 float* __restrict__ eD) {
  const int b = blockIdx.x;
  const int t = threadIdx.x;  // 0..63
  const f32x4_t* th4 = (const f32x4_t*)(thD + (size_t)b * WARR);
  const f32x4_t* a4  = (const f32x4_t*)(aD  + (size_t)b * WARR);
  u32x4_t* qp = qpD + (size_t)b * (513 * 64);
  float* eDb = eD + (size_t)b * EPLN;
  const int i0 = 4 * t + 1;

  __shared__ f32x4_t stg[18][64];  // fwd: 2 banks x (4 th + 4 a); bwd: 2 banks x 9 q

  // ================= forward =================
  float vp[4], vp2[4];
  #pragma unroll
  for (int k = 0; k < 4; ++k) { vp[k] = NEGF; vp2[k] = NEGF; }

  auto fstage = [&](int rbase, int dl) {
    #pragma unroll
    for (int q = 0; q < 4; ++q) {
      int d = dl + q; d = (d > 512) ? 512 : d;   // clamp: always real data
      __builtin_amdgcn_global_load_lds((const void*)(th4 + (size_t)d * 64 + t),
                                       (void*)&stg[rbase + q][0], 16, 0, 0);
      __builtin_amdgcn_global_load_lds((const void*)(a4 + (size_t)d * 64 + t),
                                       (void*)&stg[rbase + 4 + q][0], 16, 0, 0);
    }
  };

  fstage(0, 2);  // prologue: d=2..5 -> rows 0..7
  for (int m = 0; m < 64; ++m) {
    const int dE = 2 + 8 * m;
    DRAIN();                    // bank0 staged data ready
    fstage(8, dE + 4);          // stage bank1 (d=dE+4..dE+7)
    #pragma unroll
    for (int u = 0; u < 4; ++u) {
      const f32x4_t th = stg[u][t];
      const f32x4_t a  = stg[4 + u][t];
      const u32x4_t pk = fstep(dE + u, t, i0, th, a, vp, vp2);
      const int d = dE + u;
      qp[(size_t)(d <= 512 ? d : 0) * 64 + t] = pk;   // d=513 -> qp[0], never read
    }
    DRAIN();                    // bank1 ready
    fstage(0, dE + 8);          // stage bank0 for next m (clamped at end)
    #pragma unroll
    for (int u = 0; u < 4; ++u) {
      const f32x4_t th = stg[8 + u][t];
      const f32x4_t a  = stg[12 + u][t];
      const int d = dE + 4 + u;
      const u32x4_t pk = fstep(d, t, i0, th, a, vp, vp2);
      qp[(size_t)(d <= 512 ? d : 0) * 64 + t] = pk;
    }
  }

  DRAIN();  // all qp stores visible before backward staging reads them

  // ================= backward =================
  float ep[4], ep2[4];
  #pragma unroll
  for (int k = 0; k < 4; ++k) { ep[k] = 0.f; ep2[k] = 0.f; }

  auto bstage = [&](int rbase, int Dhi) {
    #pragma unroll
    for (int u = 0; u < 9; ++u) {
      int D = Dhi - u;
      D = (D > 512) ? 512 : D;
      D = (D < 2) ? 2 : D;      // clamp: always real data (junk slots masked)
      __builtin_amdgcn_global_load_lds((const void*)(qp + (size_t)D * 64 + t),
                                       (void*)&stg[rbase + u][0], 16, 0, 0);
    }
  };

  // block n: steps s = S..S-7, S = 513-8n; needs Q diags [S-6, S+2] = rows
  // u=0..8 (row u holds diag S+2-u). Step u reads rows u (qB=Q[s+2]) and
  // u+1 (qA=Q[s+1]).
  bstage(0, 515);  // block 0: diags 515..507 (clamped >512 -> masked uses)
  DRAIN();
  for (int n = 0; n < 64; ++n) {
    const int S = 513 - 8 * n;
    const int R  = (n & 1) ? 9 : 0;
    const int Rn = (n & 1) ? 0 : 9;
    if (n < 63) bstage(Rn, S - 6);   // next block's diags, ages over this block
    #pragma unroll
    for (int u = 0; u < 8; ++u) {
      const int s = S - u;
      const u32x4_t qB = __builtin_bit_cast(u32x4_t, stg[R + u][t]);
      const u32x4_t qA = __builtin_bit_cast(u32x4_t, stg[R + u + 1][t]);
      const f32x4_t en = bcompute(s, t, i0, qA, qB, ep, ep2);
      *(f32x4_t*)(eDb + (size_t)s * 256 + 4 * t) = en;  // diag layout
      ep2[0] = ep[0]; ep2[1] = ep[1]; ep2[2] = ep[2]; ep2[3] = ep[3];
      ep[0] = en[0]; ep[1] = en[1]; ep[2] = en[2]; ep[3] = en[3];
    }
    DRAIN();  // next bank's loads (8 steps old) complete; stores retired
  }
}

// -------- diag-layout E -> row-major aln (tiled LDS transpose) --------
// aln[b][r][c] = eD[b][r+c+2][r]
__global__ __launch_bounds__(256) void untwist(const float* __restrict__ eD,
                                               float* __restrict__ aln) {
  const int b  = blockIdx.z;
  const int r0 = blockIdx.y * 64;
  const int c0 = blockIdx.x * 64;
  const int s0 = r0 + c0 + 2;
  const int tid = threadIdx.x;
  const float* ep = eD + (size_t)b * EPLN;

  __shared__ float ld[128][65];

  const int lx = tid & 63;
  const int wy = tid >> 6;   // 0..3
  #pragma unroll
  for (int k = 0; k < 32; ++k) {
    const int sk = wy + 4 * k;               // 0..127 (s0+127 <= 513, in plane)
    ld[sk][lx] = ep[(size_t)(s0 + sk) * 256 + r0 + lx];
  }
  __syncthreads();
  #pragma unroll
  for (int k = 0; k < 16; ++k) {
    const int ry = wy + 4 * k;               // 0..63
    aln[(size_t)b * NN * MM + (size_t)(r0 + ry) * MM + c0 + lx] =
        ld[ry + lx][ry];
  }
}

// ---------------- launcher ----------------
extern "C" void kernel_launch(void* const* d_in, const int* in_sizes, int n_in,
                              void* d_out, int out_size, void* d_ws, size_t ws_size,
                              hipStream_t stream) {
  const float* zx = (const float*)d_in[0];
  const float* zy = (const float*)d_in[1];
  const float* gx = (const float*)d_in[2];
  const float* gy = (const float*)d_in[3];

  float* out   = (float*)d_out;
  float* aln   = out;                              // [B][N][M]
  float* theta = out + (size_t)BB * NN * MM;       // [B][N][M]
  float* Amat  = out + (size_t)2 * BB * NN * MM;   // [B][N][M]

  float* ws  = (float*)d_ws;
  float* thD = ws;                                    // [B][513][256] f32
  float* aD  = ws + (size_t)BB * WARR;                // [B][513][256] f32
  u32x4_t* qpD = (u32x4_t*)(ws + (size_t)2 * BB * WARR);   // [B][513][64] u32x4
  float* eD = ws + (size_t)2 * BB * WARR + (size_t)BB * 513 * 64 * 4;  // [B][514][256]

  dim3 gg(MM / 64, NN / 64, BB);
  gemm_act<0><<<gg, 256, 0, stream>>>(zx, zy, theta, thD);
  gemm_act<1><<<gg, 256, 0, stream>>>(gx, gy, Amat, aD);
  nw_wave<<<BB, 64, 0, stream>>>(thD, aD, qpD, eD);
  untwist<<<dim3(4, 4, BB), 256, 0, stream>>>(eD, aln);
}

// Round 12
// 307.423 us; speedup vs baseline: 1.2432x; 1.0754x over previous
//
#include <hip/hip_runtime.h>
#include <hip/hip_bf16.h>
#include <hip/hip_fp16.h>
#include <cstdint>
#include <cstddef>

#define BB 32
#define NN 256
#define MM 256
#define DD 512
#define NEGF (-1e9f)
#define LOG2E 1.4426950408889634f
#define WARR 131328   // 513*256 floats: one (batch, diag-array) plane
#define EPLN 131584   // 514*256 floats: E diag-layout plane

typedef __fp16 h2 __attribute__((ext_vector_type(2)));
typedef float f32x4_t __attribute__((ext_vector_type(4)));
typedef unsigned int u32x4_t __attribute__((ext_vector_type(4)));

__device__ __forceinline__ uint32_t pack_q(float a, float b) {
  h2 r = __builtin_amdgcn_cvt_pkrtz(a, b);
  return __builtin_bit_cast(uint32_t, r);
}
__device__ __forceinline__ float2 unpack_q(uint32_t u) {
  h2 r = __builtin_bit_cast(h2, u);
  return make_float2((float)r.x, (float)r.y);
}
__device__ __forceinline__ float softplus_f(float x) {
  return fmaxf(x, 0.f) + __logf(1.f + __expf(-fabsf(x)));
}
__device__ __forceinline__ float logsig_f(float x) {
  return fminf(x, 0.f) - __logf(1.f + __expf(-fabsf(x)));
}

// Counted VMEM wait (T4): never drain to 0 in the main loop. Memory clobber +
// sched_barrier pin all memory ops and consumers to their segment.
#define WAITV(N) do { \
  asm volatile("s_waitcnt vmcnt(" #N ")" ::: "memory"); \
  __builtin_amdgcn_sched_barrier(0); \
} while (0)

#define DRAIN() do { \
  asm volatile("s_waitcnt vmcnt(0) lgkmcnt(0)" ::: "memory"); \
  __builtin_amdgcn_sched_barrier(0); \
} while (0)

// ---------------- GEMM + activation + diag-layout side store ----------------
template<int OP>
__global__ __launch_bounds__(256) void gemm_act(const float* __restrict__ X,
                                                const float* __restrict__ Y,
                                                float* __restrict__ out,
                                                float* __restrict__ diag) {
  const int b  = blockIdx.z;
  const int m0 = blockIdx.y * 64;
  const int n0 = blockIdx.x * 64;
  const float* Xb = X + (size_t)b * NN * DD;
  const float* Yb = Y + (size_t)b * MM * DD;
  float* diagb = diag + (size_t)b * WARR;

  __shared__ float xs[16][68];
  __shared__ float ys[16][68];

  const int t  = threadIdx.x;
  const int tm = t >> 4;
  const int tn = t & 15;
  const int lr = t >> 2;
  const int lk = (t & 3) << 2;

  float acc[4][4];
  #pragma unroll
  for (int a = 0; a < 4; ++a)
    #pragma unroll
    for (int c = 0; c < 4; ++c) acc[a][c] = 0.f;

  for (int k0 = 0; k0 < DD; k0 += 16) {
    float4 xv = *(const float4*)(Xb + (size_t)(m0 + lr) * DD + k0 + lk);
    float4 yv = *(const float4*)(Yb + (size_t)(n0 + lr) * DD + k0 + lk);
    __syncthreads();
    xs[lk + 0][lr] = xv.x; xs[lk + 1][lr] = xv.y;
    xs[lk + 2][lr] = xv.z; xs[lk + 3][lr] = xv.w;
    ys[lk + 0][lr] = yv.x; ys[lk + 1][lr] = yv.y;
    ys[lk + 2][lr] = yv.z; ys[lk + 3][lr] = yv.w;
    __syncthreads();
    #pragma unroll
    for (int kk = 0; kk < 16; ++kk) {
      float4 xr = *(const float4*)&xs[kk][tm << 2];
      float4 yr = *(const float4*)&ys[kk][tn << 2];
      float xa[4] = {xr.x, xr.y, xr.z, xr.w};
      float ya[4] = {yr.x, yr.y, yr.z, yr.w};
      #pragma unroll
      for (int a = 0; a < 4; ++a)
        #pragma unroll
        for (int c = 0; c < 4; ++c)
          acc[a][c] = fmaf(xa[a], ya[c], acc[a][c]);
    }
  }

  #pragma unroll
  for (int a = 0; a < 4; ++a) {
    const int row = m0 + (tm << 2) + a;
    float4 o;
    float* po = (float*)&o;
    #pragma unroll
    for (int c = 0; c < 4; ++c) {
      const float v = acc[a][c];
      const float act = (OP == 0) ? softplus_f(v) : logsig_f(v);
      po[c] = act;
      const int col = n0 + (tn << 2) + c;
      diagb[(size_t)(row + col + 2) * 256 + row] = act * LOG2E;  // base-2 domain
    }
    *(float4*)(out + (size_t)b * NN * MM + (size_t)row * MM + n0 + (tn << 2)) = o;
  }
}

// ---------------- DP step helpers ----------------
__device__ __forceinline__ u32x4_t fstep(int d, int t, int i0,
                                         const f32x4_t thc, const f32x4_t ac,
                                         float vp[4], float vp2[4]) {
  float vu_in = __shfl_up(vp[3], 1);
  float vd_in = __shfl_up(vp2[3], 1);
  if (t == 0) { vu_in = NEGF; vd_in = (d == 2) ? 0.f : NEGF; }
  float vnew[4];
  u32x4_t pkv;
  #pragma unroll
  for (int k = 0; k < 4; ++k) {
    const int i = i0 + k;
    const float vu = (k == 0) ? vu_in : vp[k - 1];
    const float vd = (k == 0) ? vd_in : vp2[k - 1];
    const float vl = vp[k];
    const float a  = ac[k];
    const float th = thc[k];
    const float x0 = a + vu;
    const float x2 = a + vl;
    const float mx = fmaxf(fmaxf(x0, vd), x2);
    const float e0 = __builtin_amdgcn_exp2f(x0 - mx);
    const float e1 = __builtin_amdgcn_exp2f(vd - mx);
    const float e2 = __builtin_amdgcn_exp2f(x2 - mx);
    const float Z  = e0 + e1 + e2;
    const float rz = __builtin_amdgcn_rcpf(Z);
    const float v  = th + mx + __builtin_amdgcn_logf(Z);  // log2
    const bool valid = (i <= d - 1) && (i >= d - 256);
    vnew[k] = valid ? v : NEGF;
    pkv[k] = pack_q(e0 * rz, e2 * rz);   // (q1, q3); q2 = 1-q1-q3
  }
  #pragma unroll
  for (int k = 0; k < 4; ++k) { vp2[k] = vp[k]; vp[k] = vnew[k]; }
  return pkv;
}

__device__ __forceinline__ f32x4_t bcompute(int s, int t, int i0,
                                            u32x4_t qA, u32x4_t qB,
                                            const float ep[4], const float ep2[4]) {
  const float sh_e1 = __shfl_down(ep[0], 1);
  const float sh_e2 = __shfl_down(ep2[0], 1);
  const uint32_t sh_qA = (uint32_t)__shfl_down((int)qA.x, 1);
  const uint32_t sh_qB = (uint32_t)__shfl_down((int)qB.x, 1);
  f32x4_t en;
  #pragma unroll
  for (int k = 0; k < 4; ++k) {
    const int i = i0 + k;
    const int j = s - i;
    const bool cellv = (j >= 1) && (j <= 256);
    const uint32_t quA = (k < 3) ? qA[k + 1] : sh_qA;  // Q(s+1), row i+1
    const uint32_t quB = (k < 3) ? qB[k + 1] : sh_qB;  // Q(s+2), row i+1
    const uint32_t qcA = qA[k];                        // Q(s+1), row i
    const float2 fA = unpack_q(quA);
    const float2 fB = unpack_q(quB);
    const float2 fC = unpack_q(qcA);
    float q1u = fA.x;
    float q2d = 1.f - fB.x - fB.y;
    float q3l = fC.y;
    const float eu = (k < 3) ? ep[k + 1]  : sh_e1;
    const float ed = (k < 3) ? ep2[k + 1] : sh_e2;
    const float el = ep[k];
    q1u = (i <= 255)             ? q1u : 0.f;
    q2d = (i <= 255 && j <= 255) ? q2d : 0.f;
    q3l = (j <= 255)             ? q3l : 0.f;
    float E = q1u * eu + q2d * ed + q3l * el;
    if (s == 512 && i == 256) E = 1.f;  // terminal seed
    en[k] = cellv ? E : 0.f;
  }
  return en;
}

// -------- wave-synchronous soft-NW; LDS-staged, 3-bank, counted vmcnt ------
// One 64-lane wave per batch. global->LDS DMA staging (register-free), banks
// consumed 3 segments after issue (~12-step load age); counted vmcnt waits
// keep stores + 2 banks of loads in flight (never drain to 0 in-loop).
__global__ __launch_bounds__(64, 1) void nw_wave(const float* __restrict__ thD,
                                                 const float* __restrict__ aD,
                                                 u32x4_t* __restrict__ qpD,
                                                 float* __restrict__ eD) {
  const int b = blockIdx.x;
  const int t = threadIdx.x;  // 0..63
  const f32x4_t* th4 = (const f32x4_t*)(thD + (size_t)b * WARR);
  const f32x4_t* a4  = (const f32x4_t*)(aD  + (size_t)b * WARR);
  u32x4_t* qp = qpD + (size_t)b * (513 * 64);
  float* eDb = eD + (size_t)b * EPLN;
  const int i0 = 4 * t + 1;

  __shared__ f32x4_t stg[27][64];  // fwd: 3 banks x 8 rows; bwd: 3 banks x 9 rows

  // ================= forward =================
  float vp[4], vp2[4];
  #pragma unroll
  for (int k = 0; k < 4; ++k) { vp[k] = NEGF; vp2[k] = NEGF; }

  auto fstage = [&](int rbase, int dl) {
    #pragma unroll
    for (int q = 0; q < 4; ++q) {
      int d = dl + q; d = (d > 512) ? 512 : d;   // clamp: always real data
      __builtin_amdgcn_global_load_lds((const void*)(th4 + (size_t)d * 64 + t),
                                       (void*)&stg[rbase + q][0], 16, 0, 0);
      __builtin_amdgcn_global_load_lds((const void*)(a4 + (size_t)d * 64 + t),
                                       (void*)&stg[rbase + 4 + q][0], 16, 0, 0);
    }
  };

  fstage(0, 2); fstage(8, 6); fstage(16, 10);   // 3 banks in flight
  for (int h = 0; h < 128; ++h) {               // segments of 4 diagonals
    const int d0 = 2 + 4 * h;
    const int R = (h % 3) * 8;
    // steady state: newer-than-bank(h) = stores(4)+loads(8)+stores(4)+loads(8)=24
    if (h == 0)      WAITV(16);
    else if (h == 1) WAITV(20);
    else             WAITV(24);
    #pragma unroll
    for (int u = 0; u < 4; ++u) {
      const f32x4_t th = stg[R + u][t];
      const f32x4_t a  = stg[R + 4 + u][t];
      const int d = d0 + u;
      const u32x4_t pk = fstep(d, t, i0, th, a, vp, vp2);
      qp[(size_t)(d <= 512 ? d : 0) * 64 + t] = pk;   // d=513 -> qp[0], never read
    }
    fstage(R, d0 + 12);   // refill this bank for segment h+3
  }

  DRAIN();  // once: qp RAW boundary (backward staging reads fwd's stores)

  // ================= backward =================
  float ep[4], ep2[4];
  #pragma unroll
  for (int k = 0; k < 4; ++k) { ep[k] = 0.f; ep2[k] = 0.f; }

  auto bstage = [&](int rbase, int Dhi) {
    #pragma unroll
    for (int u = 0; u < 9; ++u) {
      int D = Dhi - u;
      D = (D > 512) ? 512 : D;
      D = (D < 2) ? 2 : D;      // clamp: always real data (junk uses masked)
      __builtin_amdgcn_global_load_lds((const void*)(qp + (size_t)D * 64 + t),
                                       (void*)&stg[rbase + u][0], 16, 0, 0);
    }
  };

  // block n: steps s = S..S-7, S = 513-8n; bank row u holds diag S+2-u.
  bstage(0, 515); bstage(9, 507); bstage(18, 499);
  for (int n = 0; n < 64; ++n) {
    const int S = 513 - 8 * n;
    const int R = (n % 3) * 9;
    // steady state: newer-than-bank(n) = 8+9+8+9 = 34
    if (n == 0)      WAITV(18);
    else if (n == 1) WAITV(26);
    else             WAITV(34);
    #pragma unroll
    for (int u = 0; u < 8; ++u) {
      const int s = S - u;
      const u32x4_t qB = __builtin_bit_cast(u32x4_t, stg[R + u][t]);
      const u32x4_t qA = __builtin_bit_cast(u32x4_t, stg[R + u + 1][t]);
      const f32x4_t en = bcompute(s, t, i0, qA, qB, ep, ep2);
      *(f32x4_t*)(eDb + (size_t)s * 256 + 4 * t) = en;  // diag layout
      ep2[0] = ep[0]; ep2[1] = ep[1]; ep2[2] = ep[2]; ep2[3] = ep[3];
      ep[0] = en[0]; ep[1] = en[1]; ep[2] = en[2]; ep[3] = en[3];
    }
    bstage(R, S - 22);   // refill this bank for block n+3 (Dhi' = (S-24)+2)
  }
}

// -------- diag-layout E -> row-major aln (tiled LDS transpose) --------
// aln[b][r][c] = eD[b][r+c+2][r]
__global__ __launch_bounds__(256) void untwist(const float* __restrict__ eD,
                                               float* __restrict__ aln) {
  const int b  = blockIdx.z;
  const int r0 = blockIdx.y * 64;
  const int c0 = blockIdx.x * 64;
  const int s0 = r0 + c0 + 2;
  const int tid = threadIdx.x;
  const float* ep = eD + (size_t)b * EPLN;

  __shared__ float ld[128][65];

  const int lx = tid & 63;
  const int wy = tid >> 6;   // 0..3
  #pragma unroll
  for (int k = 0; k < 32; ++k) {
    const int sk = wy + 4 * k;               // 0..127 (s0+127 <= 513, in plane)
    ld[sk][lx] = ep[(size_t)(s0 + sk) * 256 + r0 + lx];
  }
  __syncthreads();
  #pragma unroll
  for (int k = 0; k < 16; ++k) {
    const int ry = wy + 4 * k;               // 0..63
    aln[(size_t)b * NN * MM + (size_t)(r0 + ry) * MM + c0 + lx] =
        ld[ry + lx][ry];
  }
}

// ---------------- launcher ----------------
extern "C" void kernel_launch(void* const* d_in, const int* in_sizes, int n_in,
                              void* d_out, int out_size, void* d_ws, size_t ws_size,
                              hipStream_t stream) {
  const float* zx = (const float*)d_in[0];
  const float* zy = (const float*)d_in[1];
  const float* gx = (const float*)d_in[2];
  const float* gy = (const float*)d_in[3];

  float* out   = (float*)d_out;
  float* aln   = out;                              // [B][N][M]
  float* theta = out + (size_t)BB * NN * MM;       // [B][N][M]
  float* Amat  = out + (size_t)2 * BB * NN * MM;   // [B][N][M]

  float* ws  = (float*)d_ws;
  float* thD = ws;                                    // [B][513][256] f32
  float* aD  = ws + (size_t)BB * WARR;                // [B][513][256] f32
  u32x4_t* qpD = (u32x4_t*)(ws + (size_t)2 * BB * WARR);   // [B][513][64] u32x4
  float* eD = ws + (size_t)2 * BB * WARR + (size_t)BB * 513 * 64 * 4;  // [B][514][256]

  dim3 gg(MM / 64, NN / 64, BB);
  gemm_act<0><<<gg, 256, 0, stream>>>(zx, zy, theta, thD);
  gemm_act<1><<<gg, 256, 0, stream>>>(gx, gy, Amat, aD);
  nw_wave<<<BB, 64, 0, stream>>>(thD, aD, qpD, eD);
  untwist<<<dim3(4, 4, BB), 256, 0, stream>>>(eD, aln);
}

// Round 13
// 224.274 us; speedup vs baseline: 1.7041x; 1.3708x over previous
//
#include <hip/hip_runtime.h>
#include <hip/hip_bf16.h>
#include <hip/hip_fp16.h>
#include <cstdint>
#include <cstddef>

#define BB 32
#define NN 256
#define MM 256
#define DD 512
#define NEGF (-1e9f)
#define LOG2E 1.4426950408889634f
#define SPLN 82176   // 321*256 floats: th/a skew planes per batch
#define QPLN 82176   // 321*64 u32x4 = 82176 4-byte words per batch
#define EPLN 81920   // 320*256 floats: E skew planes per batch

typedef __fp16 h2 __attribute__((ext_vector_type(2)));
typedef float f32x4_t __attribute__((ext_vector_type(4)));
typedef unsigned int u32x4_t __attribute__((ext_vector_type(4)));

__device__ __forceinline__ uint32_t pack_q(float a, float b) {
  h2 r = __builtin_amdgcn_cvt_pkrtz(a, b);
  return __builtin_bit_cast(uint32_t, r);
}
__device__ __forceinline__ float2 unpack_q(uint32_t u) {
  h2 r = __builtin_bit_cast(h2, u);
  return make_float2((float)r.x, (float)r.y);
}
__device__ __forceinline__ float softplus_f(float x) {
  return fmaxf(x, 0.f) + __logf(1.f + __expf(-fabsf(x)));
}
__device__ __forceinline__ float logsig_f(float x) {
  return fminf(x, 0.f) - __logf(1.f + __expf(-fabsf(x)));
}

#define WAITV(N) do { \
  asm volatile("s_waitcnt vmcnt(" #N ")" ::: "memory"); \
  __builtin_amdgcn_sched_barrier(0); \
} while (0)

#define DRAIN() do { \
  asm volatile("s_waitcnt vmcnt(0) lgkmcnt(0)" ::: "memory"); \
  __builtin_amdgcn_sched_barrier(0); \
} while (0)

// ---------------- GEMM + activation + SKEW-layout side store ----------------
// Skew plane for cell (row, col) [0-indexed]: m = col + 1 + (row>>2), slot row.
template<int OP>
__global__ __launch_bounds__(256) void gemm_act(const float* __restrict__ X,
                                                const float* __restrict__ Y,
                                                float* __restrict__ out,
                                                float* __restrict__ skew) {
  const int b  = blockIdx.z;
  const int m0 = blockIdx.y * 64;
  const int n0 = blockIdx.x * 64;
  const float* Xb = X + (size_t)b * NN * DD;
  const float* Yb = Y + (size_t)b * MM * DD;
  float* skb = skew + (size_t)b * SPLN;

  __shared__ float xs[16][68];
  __shared__ float ys[16][68];

  const int t  = threadIdx.x;
  const int tm = t >> 4;
  const int tn = t & 15;
  const int lr = t >> 2;
  const int lk = (t & 3) << 2;

  float acc[4][4];
  #pragma unroll
  for (int a = 0; a < 4; ++a)
    #pragma unroll
    for (int c = 0; c < 4; ++c) acc[a][c] = 0.f;

  for (int k0 = 0; k0 < DD; k0 += 16) {
    float4 xv = *(const float4*)(Xb + (size_t)(m0 + lr) * DD + k0 + lk);
    float4 yv = *(const float4*)(Yb + (size_t)(n0 + lr) * DD + k0 + lk);
    __syncthreads();
    xs[lk + 0][lr] = xv.x; xs[lk + 1][lr] = xv.y;
    xs[lk + 2][lr] = xv.z; xs[lk + 3][lr] = xv.w;
    ys[lk + 0][lr] = yv.x; ys[lk + 1][lr] = yv.y;
    ys[lk + 2][lr] = yv.z; ys[lk + 3][lr] = yv.w;
    __syncthreads();
    #pragma unroll
    for (int kk = 0; kk < 16; ++kk) {
      float4 xr = *(const float4*)&xs[kk][tm << 2];
      float4 yr = *(const float4*)&ys[kk][tn << 2];
      float xa[4] = {xr.x, xr.y, xr.z, xr.w};
      float ya[4] = {yr.x, yr.y, yr.z, yr.w};
      #pragma unroll
      for (int a = 0; a < 4; ++a)
        #pragma unroll
        for (int c = 0; c < 4; ++c)
          acc[a][c] = fmaf(xa[a], ya[c], acc[a][c]);
    }
  }

  #pragma unroll
  for (int a = 0; a < 4; ++a) {
    const int row = m0 + (tm << 2) + a;
    float4 o;
    float* po = (float*)&o;
    #pragma unroll
    for (int c = 0; c < 4; ++c) {
      const float v = acc[a][c];
      const float act = (OP == 0) ? softplus_f(v) : logsig_f(v);
      po[c] = act;
      const int col = n0 + (tn << 2) + c;
      skb[(size_t)(col + 1 + (row >> 2)) * 256 + row] = act * LOG2E;  // base-2
    }
    *(float4*)(out + (size_t)b * NN * MM + (size_t)row * MM + n0 + (tn << 2)) = o;
  }
}

// -------- wave-synchronous soft-NW, SKEWED schedule, LDS-staged ------------
// Lane t owns grid rows 4t+1..4t+4. Fwd step m (1..320): lane t at column
// j = m - t. Bwd step m' (0..319): lane t at column j = 319 - m' - t. 640
// total steps vs 1023 anti-diagonal steps. 3-bank global_load_lds staging,
// counted vmcnt (never 0 in-loop).
__global__ __launch_bounds__(64, 1) void nw_wave(const float* __restrict__ thSA,
                                                 const float* __restrict__ aSA,
                                                 u32x4_t* __restrict__ qSA,
                                                 float* __restrict__ eSA) {
  const int b = blockIdx.x;
  const int t = threadIdx.x;  // 0..63
  const float* thS = thSA + (size_t)b * SPLN;
  const float* aS  = aSA  + (size_t)b * SPLN;
  u32x4_t* qS = qSA + (size_t)b * (QPLN / 4);
  float* eSb = eSA + (size_t)b * EPLN;

  __shared__ f32x4_t stg[24][64];  // fwd: 3 banks x 8 rows; bwd: 3 banks x 4

  // ================= forward =================
  float vp[4];
  #pragma unroll
  for (int k = 0; k < 4; ++k) vp[k] = NEGF;
  float v3m1 = NEGF, v3m2 = NEGF;  // own vn[3] history (for lane t+1's borders)

  auto fstage = [&](int rbase, int mlo) {
    #pragma unroll
    for (int q = 0; q < 4; ++q) {
      int m = mlo + q; m = m < 1 ? 1 : (m > 320 ? 320 : m);
      __builtin_amdgcn_global_load_lds((const void*)(thS + (size_t)m * 256 + 4 * t),
                                       (void*)&stg[rbase + q][0], 16, 0, 0);
      __builtin_amdgcn_global_load_lds((const void*)(aS + (size_t)m * 256 + 4 * t),
                                       (void*)&stg[rbase + 4 + q][0], 16, 0, 0);
    }
  };

  fstage(0, 1); fstage(8, 5); fstage(16, 9);
  for (int h = 0; h < 80; ++h) {
    const int m0 = 1 + 4 * h;
    const int R = (h % 3) * 8;
    if (h == 0)      WAITV(16);
    else if (h == 1) WAITV(20);
    else             WAITV(24);
    #pragma unroll
    for (int u = 0; u < 4; ++u) {
      const int m = m0 + u;
      const f32x4_t th4 = stg[R + u][t];
      const f32x4_t a4  = stg[R + 4 + u][t];
      const int j = m - t;
      const bool act = (j >= 1) && (j <= 256);
      float vu_in = __shfl_up(v3m1, 1);
      float vd_in = __shfl_up(v3m2, 1);
      if (t == 0) { vu_in = NEGF; vd_in = (m == 1) ? 0.f : NEGF; }
      float vn[4];
      uint32_t pk[4];
      #pragma unroll
      for (int k = 0; k < 4; ++k) {
        const float vu = (k == 0) ? vu_in : vn[k - 1];   // V[i-1][j] (this step)
        const float vd = (k == 0) ? vd_in : vp[k - 1];   // V[i-1][j-1]
        const float vl = vp[k];                          // V[i][j-1]
        const float a  = a4[k];
        const float th = th4[k];
        const float x0 = a + vu;
        const float x2 = a + vl;
        const float mx = fmaxf(fmaxf(x0, vd), x2);
        const float e0 = __builtin_amdgcn_exp2f(x0 - mx);
        const float e1 = __builtin_amdgcn_exp2f(vd - mx);
        const float e2 = __builtin_amdgcn_exp2f(x2 - mx);
        const float Z  = e0 + e1 + e2;
        const float rz = __builtin_amdgcn_rcpf(Z);
        const float v  = th + mx + __builtin_amdgcn_logf(Z);  // log2
        vn[k] = act ? v : vp[k];   // keep old when inactive (kills NaN too)
        pk[k] = pack_q(e0 * rz, e2 * rz);   // (q1, q3); q2 = 1-q1-q3
      }
      qS[(size_t)m * 64 + t] = u32x4_t{pk[0], pk[1], pk[2], pk[3]};
      v3m2 = v3m1; v3m1 = vn[3];
      #pragma unroll
      for (int k = 0; k < 4; ++k) vp[k] = vn[k];
    }
    fstage(R, m0 + 12);
  }

  DRAIN();  // qS RAW boundary: bwd staging reads fwd's stores

  // ================= backward =================
  float ep[4] = {0.f, 0.f, 0.f, 0.f};
  float e0m1 = 0.f, e0m2 = 0.f;           // own en[0] history (for lane t-1)
  u32x4_t qm1 = {0, 0, 0, 0}, qm2 = qm1;  // plane P+1 / P+2 rows (own lane)

  auto bstage = [&](int rbase, int Phi) {
    #pragma unroll
    for (int u = 0; u < 4; ++u) {
      int P = Phi - u; P = P < 0 ? 0 : (P > 320 ? 320 : P);
      __builtin_amdgcn_global_load_lds((const void*)(qS + (size_t)P * 64 + t),
                                       (void*)&stg[rbase + u][0], 16, 0, 0);
    }
  };

  bstage(0, 319); bstage(4, 315); bstage(8, 311);
  for (int n = 0; n < 80; ++n) {
    const int R = (n % 3) * 4;
    if (n == 0)      WAITV(8);
    else if (n == 1) WAITV(12);
    else             WAITV(16);
    #pragma unroll
    for (int u = 0; u < 4; ++u) {
      const int mp = 4 * n + u;        // 0..319
      const int P  = 319 - mp;
      const u32x4_t cur = __builtin_bit_cast(u32x4_t, stg[R + u][t]);
      const int j = P - t;
      const bool act = (j >= 1) && (j <= 256);
      const float sh_e1 = __shfl_down(e0m1, 1);
      const float sh_e2 = __shfl_down(e0m2, 1);
      const uint32_t sh_q1 = (uint32_t)__shfl_down((int)qm1[0], 1);
      const uint32_t sh_q2 = (uint32_t)__shfl_down((int)qm2[0], 1);
      float en[4];
      #pragma unroll
      for (int kk = 0; kk < 4; ++kk) {
        const int k = 3 - kk;          // serial: k = 3 -> 0
        const int i = 4 * t + 1 + k;
        const uint32_t uA = (k < 3) ? cur[k + 1] : sh_q1;  // Q of (i+1, j)
        const uint32_t uB = (k < 3) ? qm1[k + 1] : sh_q2;  // Q of (i+1, j+1)
        const uint32_t uC = qm1[k];                        // Q of (i,   j+1)
        const float2 fA = unpack_q(uA);
        const float2 fB = unpack_q(uB);
        const float2 fC = unpack_q(uC);
        const float q1u = (i <= 255)             ? fA.x : 0.f;
        const float q2d = (i <= 255 && j <= 255) ? (1.f - fB.x - fB.y) : 0.f;
        const float q3l = (j <= 255)             ? fC.y : 0.f;
        const float eu = (k < 3) ? en[k + 1] : sh_e1;  // E[i+1][j]
        const float ed = (k < 3) ? ep[k + 1] : sh_e2;  // E[i+1][j+1]
        const float el = ep[k];                        // E[i][j+1]
        float E = q1u * eu + q2d * ed + q3l * el;
        if (i == 256 && j == 256) E = 1.f;   // terminal seed (m'=0, lane 63)
        en[k] = act ? E : 0.f;               // sanitize (kills NaN)
      }
      *(f32x4_t*)(eSb + (size_t)mp * 256 + 4 * t) =
          f32x4_t{en[0], en[1], en[2], en[3]};
      ep[0] = en[0]; ep[1] = en[1]; ep[2] = en[2]; ep[3] = en[3];
      e0m2 = e0m1; e0m1 = en[0];
      qm2 = qm1; qm1 = cur;
    }
    bstage(R, 307 - 4 * n);   // planes for segment n+3
  }
}

// -------- skew-layout E -> row-major aln (tiled LDS transpose) --------
// aln[b][r][c] = eS[b][318 - c - (r>>2)][r]
__global__ __launch_bounds__(256) void untwist(const float* __restrict__ eS,
                                               float* __restrict__ aln) {
  const int b  = blockIdx.z;
  const int r0 = blockIdx.y * 64;
  const int c0 = blockIdx.x * 64;
  const int tid = threadIdx.x;
  const float* ep = eS + (size_t)b * EPLN;

  __shared__ float ld[80][65];

  const int lx = tid & 63;
  const int wy = tid >> 6;   // 0..3
  const int mbase = 240 - c0 - (r0 >> 2);   // lowest plane touched by tile
  #pragma unroll
  for (int k = 0; k < 20; ++k) {
    const int p = wy + 4 * k;               // 0..79 (mbase+79 <= 319)
    ld[p][lx] = ep[(size_t)(mbase + p) * 256 + r0 + lx];
  }
  __syncthreads();
  #pragma unroll
  for (int k = 0; k < 16; ++k) {
    const int rr = wy + 4 * k;              // 0..63
    aln[(size_t)b * NN * MM + (size_t)(r0 + rr) * MM + c0 + lx] =
        ld[78 - lx - (rr >> 2)][rr];
  }
}

// ---------------- launcher ----------------
extern "C" void kernel_launch(void* const* d_in, const int* in_sizes, int n_in,
                              void* d_out, int out_size, void* d_ws, size_t ws_size,
                              hipStream_t stream) {
  const float* zx = (const float*)d_in[0];
  const float* zy = (const float*)d_in[1];
  const float* gx = (const float*)d_in[2];
  const float* gy = (const float*)d_in[3];

  float* out   = (float*)d_out;
  float* aln   = out;                              // [B][N][M]
  float* theta = out + (size_t)BB * NN * MM;       // [B][N][M]
  float* Amat  = out + (size_t)2 * BB * NN * MM;   // [B][N][M]

  float* ws  = (float*)d_ws;
  float* thS = ws;                                   // [B][321][256] f32
  float* aS  = ws + (size_t)BB * SPLN;               // [B][321][256] f32
  u32x4_t* qS = (u32x4_t*)(ws + (size_t)2 * BB * SPLN);  // [B][321][64] u32x4
  float* eS = ws + (size_t)3 * BB * SPLN;            // [B][320][256] f32

  dim3 gg(MM / 64, NN / 64, BB);
  gemm_act<0><<<gg, 256, 0, stream>>>(zx, zy, theta, thS);
  gemm_act<1><<<gg, 256, 0, stream>>>(gx, gy, Amat, aS);
  nw_wave<<<BB, 64, 0, stream>>>(thS, aS, qS, eS);
  untwist<<<dim3(4, 4, BB), 256, 0, stream>>>(eS, aln);
}

// Round 14
// 183.625 us; speedup vs baseline: 2.0813x; 1.2214x over previous
//
#include <hip/hip_runtime.h>
#include <hip/hip_bf16.h>
#include <hip/hip_fp16.h>
#include <cstdint>
#include <cstddef>

#define BB 32
#define NN 256
#define MM 256
#define DD 512
#define NEGF (-1e9f)
#define LOG2E 1.4426950408889634f
#define SPLN 82176   // 321*256 floats: th/a skew planes per batch
#define QPLN 82176   // 321*64 u32x4 = 82176 4-byte words per batch
#define EPLN 81920   // 320*256 floats: E skew planes per batch

typedef __fp16 h2 __attribute__((ext_vector_type(2)));
typedef float f32x4_t __attribute__((ext_vector_type(4)));
typedef unsigned int u32x4_t __attribute__((ext_vector_type(4)));
typedef short s16x8 __attribute__((ext_vector_type(8)));

__device__ __forceinline__ uint32_t pack_q(float a, float b) {
  h2 r = __builtin_amdgcn_cvt_pkrtz(a, b);
  return __builtin_bit_cast(uint32_t, r);
}
__device__ __forceinline__ float2 unpack_q(uint32_t u) {
  h2 r = __builtin_bit_cast(h2, u);
  return make_float2((float)r.x, (float)r.y);
}
__device__ __forceinline__ float softplus_f(float x) {
  return fmaxf(x, 0.f) + __logf(1.f + __expf(-fabsf(x)));
}
__device__ __forceinline__ float logsig_f(float x) {
  return fminf(x, 0.f) - __logf(1.f + __expf(-fabsf(x)));
}
__device__ __forceinline__ short f2bf(float f) {   // RNE f32 -> bf16 bits
  uint32_t u = __builtin_bit_cast(uint32_t, f);
  u += 0x7FFFu + ((u >> 16) & 1u);
  return (short)(u >> 16);
}

#define WAITV(N) do { \
  asm volatile("s_waitcnt vmcnt(" #N ")" ::: "memory"); \
  __builtin_amdgcn_sched_barrier(0); \
} while (0)

#define DRAIN() do { \
  asm volatile("s_waitcnt vmcnt(0) lgkmcnt(0)" ::: "memory"); \
  __builtin_amdgcn_sched_barrier(0); \
} while (0)

// ---------- bf16-MFMA GEMM + activation + skew side store (both ops) -------
// z = op*32 + b. C = X @ Y^T per batch, 64x64 tile/block, 4 waves (32x32 ea).
// A/B frag (16x16x32 bf16): lane l -> row/col (l&15), k = (l>>4)*8 + 0..7.
// C/D frag: col = l&15, row = (l>>4)*4 + reg (m89/m91-verified).
__global__ __launch_bounds__(256) void gemm_mfma(const float* __restrict__ ZX,
                                                 const float* __restrict__ ZY,
                                                 const float* __restrict__ GX,
                                                 const float* __restrict__ GY,
                                                 float* __restrict__ theta,
                                                 float* __restrict__ Amat,
                                                 float* __restrict__ thS,
                                                 float* __restrict__ aS) {
  const int z  = blockIdx.z;
  const int b  = z & 31;
  const int op = z >> 5;
  const int ty = blockIdx.y;   // row tile (64)
  const int tx = blockIdx.x;   // col tile (64)
  const float* Xb = (op ? GX : ZX) + (size_t)b * NN * DD;
  const float* Yb = (op ? GY : ZY) + (size_t)b * MM * DD;
  float* outb = (op ? Amat : theta) + (size_t)b * NN * MM;
  float* skb  = (op ? aS : thS) + (size_t)b * SPLN;

  __shared__ short xs[64][40];   // 64 rows x 32 bf16 (+8 pad), 80B stride
  __shared__ short ys[64][40];

  const int tid = threadIdx.x;
  const int l   = tid & 63;
  const int w   = tid >> 6;          // wave 0..3
  const int r0  = (w >> 1) * 32;     // quadrant row base
  const int c0  = (w & 1) * 32;      // quadrant col base
  const int srow = tid >> 2;         // staging row 0..63
  const int scg  = (tid & 3) * 8;    // staging k-group 0,8,16,24

  f32x4_t acc[2][2];
  #pragma unroll
  for (int i = 0; i < 2; ++i)
    #pragma unroll
    for (int j = 0; j < 2; ++j) acc[i][j] = f32x4_t{0.f, 0.f, 0.f, 0.f};

  const int lr = l & 15;         // frag row/col within 16
  const int kof = (l >> 4) * 8;  // frag k offset

  for (int ks = 0; ks < 16; ++ks) {
    const int k0 = ks * 32;
    const float4 xv0 = *(const float4*)(Xb + (size_t)(ty * 64 + srow) * DD + k0 + scg);
    const float4 xv1 = *(const float4*)(Xb + (size_t)(ty * 64 + srow) * DD + k0 + scg + 4);
    const float4 yv0 = *(const float4*)(Yb + (size_t)(tx * 64 + srow) * DD + k0 + scg);
    const float4 yv1 = *(const float4*)(Yb + (size_t)(tx * 64 + srow) * DD + k0 + scg + 4);
    __syncthreads();   // protect previous iteration's frag reads
    s16x8 xp, yp;
    xp[0] = f2bf(xv0.x); xp[1] = f2bf(xv0.y); xp[2] = f2bf(xv0.z); xp[3] = f2bf(xv0.w);
    xp[4] = f2bf(xv1.x); xp[5] = f2bf(xv1.y); xp[6] = f2bf(xv1.z); xp[7] = f2bf(xv1.w);
    yp[0] = f2bf(yv0.x); yp[1] = f2bf(yv0.y); yp[2] = f2bf(yv0.z); yp[3] = f2bf(yv0.w);
    yp[4] = f2bf(yv1.x); yp[5] = f2bf(yv1.y); yp[6] = f2bf(yv1.z); yp[7] = f2bf(yv1.w);
    *(s16x8*)&xs[srow][scg] = xp;
    *(s16x8*)&ys[srow][scg] = yp;
    __syncthreads();
    const s16x8 a0 = *(const s16x8*)&xs[r0 + lr][kof];
    const s16x8 a1 = *(const s16x8*)&xs[r0 + 16 + lr][kof];
    const s16x8 b0 = *(const s16x8*)&ys[c0 + lr][kof];
    const s16x8 b1 = *(const s16x8*)&ys[c0 + 16 + lr][kof];
    acc[0][0] = __builtin_amdgcn_mfma_f32_16x16x32_bf16(a0, b0, acc[0][0], 0, 0, 0);
    acc[0][1] = __builtin_amdgcn_mfma_f32_16x16x32_bf16(a0, b1, acc[0][1], 0, 0, 0);
    acc[1][0] = __builtin_amdgcn_mfma_f32_16x16x32_bf16(a1, b0, acc[1][0], 0, 0, 0);
    acc[1][1] = __builtin_amdgcn_mfma_f32_16x16x32_bf16(a1, b1, acc[1][1], 0, 0, 0);
  }

  #pragma unroll
  for (int i = 0; i < 2; ++i) {
    #pragma unroll
    for (int j = 0; j < 2; ++j) {
      #pragma unroll
      for (int r = 0; r < 4; ++r) {
        const int R = ty * 64 + r0 + i * 16 + (l >> 4) * 4 + r;  // global row
        const int C = tx * 64 + c0 + j * 16 + (l & 15);          // global col
        const float v = acc[i][j][r];
        const float act = (op == 0) ? softplus_f(v) : logsig_f(v);
        outb[(size_t)R * MM + C] = act;
        skb[(size_t)(C + 1 + (R >> 2)) * 256 + R] = act * LOG2E;  // base-2
      }
    }
  }
}

// -------- wave-synchronous soft-NW, SKEWED schedule, LDS-staged ------------
__global__ __launch_bounds__(64, 1) void nw_wave(const float* __restrict__ thSA,
                                                 const float* __restrict__ aSA,
                                                 u32x4_t* __restrict__ qSA,
                                                 float* __restrict__ eSA) {
  const int b = blockIdx.x;
  const int t = threadIdx.x;  // 0..63
  const float* thS = thSA + (size_t)b * SPLN;
  const float* aS  = aSA  + (size_t)b * SPLN;
  u32x4_t* qS = qSA + (size_t)b * (QPLN / 4);
  float* eSb = eSA + (size_t)b * EPLN;

  __shared__ f32x4_t stg[24][64];  // fwd: 3 banks x 8 rows; bwd: 3 banks x 4

  // ================= forward =================
  float vp[4];
  #pragma unroll
  for (int k = 0; k < 4; ++k) vp[k] = NEGF;
  float v3m1 = NEGF, v3m2 = NEGF;

  auto fstage = [&](int rbase, int mlo) {
    #pragma unroll
    for (int q = 0; q < 4; ++q) {
      int m = mlo + q; m = m < 1 ? 1 : (m > 320 ? 320 : m);
      __builtin_amdgcn_global_load_lds((const void*)(thS + (size_t)m * 256 + 4 * t),
                                       (void*)&stg[rbase + q][0], 16, 0, 0);
      __builtin_amdgcn_global_load_lds((const void*)(aS + (size_t)m * 256 + 4 * t),
                                       (void*)&stg[rbase + 4 + q][0], 16, 0, 0);
    }
  };

  fstage(0, 1); fstage(8, 5); fstage(16, 9);
  for (int h = 0; h < 80; ++h) {
    const int m0 = 1 + 4 * h;
    const int R = (h % 3) * 8;
    if (h == 0)      WAITV(16);
    else if (h == 1) WAITV(20);
    else             WAITV(24);
    #pragma unroll
    for (int u = 0; u < 4; ++u) {
      const int m = m0 + u;
      const f32x4_t th4 = stg[R + u][t];
      const f32x4_t a4  = stg[R + 4 + u][t];
      const int j = m - t;
      const bool act = (j >= 1) && (j <= 256);
      float vu_in = __shfl_up(v3m1, 1);
      float vd_in = __shfl_up(v3m2, 1);
      if (t == 0) { vu_in = NEGF; vd_in = (m == 1) ? 0.f : NEGF; }
      float vn[4];
      uint32_t pk[4];
      #pragma unroll
      for (int k = 0; k < 4; ++k) {
        const float vu = (k == 0) ? vu_in : vn[k - 1];
        const float vd = (k == 0) ? vd_in : vp[k - 1];
        const float vl = vp[k];
        const float a  = a4[k];
        const float th = th4[k];
        const float x0 = a + vu;
        const float x2 = a + vl;
        const float mx = fmaxf(fmaxf(x0, vd), x2);
        const float e0 = __builtin_amdgcn_exp2f(x0 - mx);
        const float e1 = __builtin_amdgcn_exp2f(vd - mx);
        const float e2 = __builtin_amdgcn_exp2f(x2 - mx);
        const float Z  = e0 + e1 + e2;
        const float rz = __builtin_amdgcn_rcpf(Z);
        const float v  = th + mx + __builtin_amdgcn_logf(Z);  // log2
        vn[k] = act ? v : vp[k];
        pk[k] = pack_q(e0 * rz, e2 * rz);
      }
      qS[(size_t)m * 64 + t] = u32x4_t{pk[0], pk[1], pk[2], pk[3]};
      v3m2 = v3m1; v3m1 = vn[3];
      #pragma unroll
      for (int k = 0; k < 4; ++k) vp[k] = vn[k];
    }
    fstage(R, m0 + 12);
  }

  DRAIN();  // qS RAW boundary

  // ================= backward =================
  float ep[4] = {0.f, 0.f, 0.f, 0.f};
  float e0m1 = 0.f, e0m2 = 0.f;
  u32x4_t qm1 = {0, 0, 0, 0}, qm2 = qm1;

  auto bstage = [&](int rbase, int Phi) {
    #pragma unroll
    for (int u = 0; u < 4; ++u) {
      int P = Phi - u; P = P < 0 ? 0 : (P > 320 ? 320 : P);
      __builtin_amdgcn_global_load_lds((const void*)(qS + (size_t)P * 64 + t),
                                       (void*)&stg[rbase + u][0], 16, 0, 0);
    }
  };

  bstage(0, 319); bstage(4, 315); bstage(8, 311);
  for (int n = 0; n < 80; ++n) {
    const int R = (n % 3) * 4;
    if (n == 0)      WAITV(8);
    else if (n == 1) WAITV(12);
    else             WAITV(16);
    #pragma unroll
    for (int u = 0; u < 4; ++u) {
      const int mp = 4 * n + u;
      const int P  = 319 - mp;
      const u32x4_t cur = __builtin_bit_cast(u32x4_t, stg[R + u][t]);
      const int j = P - t;
      const bool act = (j >= 1) && (j <= 256);
      const float sh_e1 = __shfl_down(e0m1, 1);
      const float sh_e2 = __shfl_down(e0m2, 1);
      const uint32_t sh_q1 = (uint32_t)__shfl_down((int)qm1[0], 1);
      const uint32_t sh_q2 = (uint32_t)__shfl_down((int)qm2[0], 1);
      float en[4];
      #pragma unroll
      for (int kk = 0; kk < 4; ++kk) {
        const int k = 3 - kk;
        const int i = 4 * t + 1 + k;
        const uint32_t uA = (k < 3) ? cur[k + 1] : sh_q1;
        const uint32_t uB = (k < 3) ? qm1[k + 1] : sh_q2;
        const uint32_t uC = qm1[k];
        const float2 fA = unpack_q(uA);
        const float2 fB = unpack_q(uB);
        const float2 fC = unpack_q(uC);
        const float q1u = (i <= 255)             ? fA.x : 0.f;
        const float q2d = (i <= 255 && j <= 255) ? (1.f - fB.x - fB.y) : 0.f;
        const float q3l = (j <= 255)             ? fC.y : 0.f;
        const float eu = (k < 3) ? en[k + 1] : sh_e1;
        const float ed = (k < 3) ? ep[k + 1] : sh_e2;
        const float el = ep[k];
        float E = q1u * eu + q2d * ed + q3l * el;
        if (i == 256 && j == 256) E = 1.f;
        en[k] = act ? E : 0.f;
      }
      *(f32x4_t*)(eSb + (size_t)mp * 256 + 4 * t) =
          f32x4_t{en[0], en[1], en[2], en[3]};
      ep[0] = en[0]; ep[1] = en[1]; ep[2] = en[2]; ep[3] = en[3];
      e0m2 = e0m1; e0m1 = en[0];
      qm2 = qm1; qm1 = cur;
    }
    bstage(R, 307 - 4 * n);
  }
}

// -------- skew-layout E -> row-major aln (tiled LDS transpose) --------
__global__ __launch_bounds__(256) void untwist(const float* __restrict__ eS,
                                               float* __restrict__ aln) {
  const int b  = blockIdx.z;
  const int r0 = blockIdx.y * 64;
  const int c0 = blockIdx.x * 64;
  const int tid = threadIdx.x;
  const float* ep = eS + (size_t)b * EPLN;

  __shared__ float ld[80][65];

  const int lx = tid & 63;
  const int wy = tid >> 6;
  const int mbase = 240 - c0 - (r0 >> 2);
  #pragma unroll
  for (int k = 0; k < 20; ++k) {
    const int p = wy + 4 * k;
    ld[p][lx] = ep[(size_t)(mbase + p) * 256 + r0 + lx];
  }
  __syncthreads();
  #pragma unroll
  for (int k = 0; k < 16; ++k) {
    const int rr = wy + 4 * k;
    aln[(size_t)b * NN * MM + (size_t)(r0 + rr) * MM + c0 + lx] =
        ld[78 - lx - (rr >> 2)][rr];
  }
}

// ---------------- launcher ----------------
extern "C" void kernel_launch(void* const* d_in, const int* in_sizes, int n_in,
                              void* d_out, int out_size, void* d_ws, size_t ws_size,
                              hipStream_t stream) {
  const float* zx = (const float*)d_in[0];
  const float* zy = (const float*)d_in[1];
  const float* gx = (const float*)d_in[2];
  const float* gy = (const float*)d_in[3];

  float* out   = (float*)d_out;
  float* aln   = out;                              // [B][N][M]
  float* theta = out + (size_t)BB * NN * MM;       // [B][N][M]
  float* Amat  = out + (size_t)2 * BB * NN * MM;   // [B][N][M]

  float* ws  = (float*)d_ws;
  float* thS = ws;                                   // [B][321][256] f32
  float* aS  = ws + (size_t)BB * SPLN;               // [B][321][256] f32
  u32x4_t* qS = (u32x4_t*)(ws + (size_t)2 * BB * SPLN);  // [B][321][64] u32x4
  float* eS = ws + (size_t)3 * BB * SPLN;            // [B][320][256] f32

  gemm_mfma<<<dim3(4, 4, 64), 256, 0, stream>>>(zx, zy, gx, gy,
                                                theta, Amat, thS, aS);
  nw_wave<<<BB, 64, 0, stream>>>(thS, aS, qS, eS);
  untwist<<<dim3(4, 4, BB), 256, 0, stream>>>(eS, aln);
}

// Round 15
// 170.310 us; speedup vs baseline: 2.2440x; 1.0782x over previous
//
#include <hip/hip_runtime.h>
#include <hip/hip_bf16.h>
#include <hip/hip_fp16.h>
#include <cstdint>
#include <cstddef>

#define BB 32
#define NN 256
#define MM 256
#define DD 512
#define NEGF (-1e9f)
#define LOG2E 1.4426950408889634f
#define SPLN 82176   // 321*256 floats: th/a skew planes per batch
#define QPLN 82176   // 321*64 u32x4 words-of-4B per batch
#define EPLN 81920   // 320*256 floats: E skew planes per batch

typedef __fp16 h2 __attribute__((ext_vector_type(2)));
typedef float f32x4_t __attribute__((ext_vector_type(4)));
typedef unsigned int u32x4_t __attribute__((ext_vector_type(4)));
typedef short s16x8 __attribute__((ext_vector_type(8)));

__device__ __forceinline__ uint32_t pack_q(float a, float b) {
  h2 r = __builtin_amdgcn_cvt_pkrtz(a, b);
  return __builtin_bit_cast(uint32_t, r);
}
__device__ __forceinline__ float2 unpack_q(uint32_t u) {
  h2 r = __builtin_bit_cast(h2, u);
  return make_float2((float)r.x, (float)r.y);
}
__device__ __forceinline__ float softplus_f(float x) {
  return fmaxf(x, 0.f) + __logf(1.f + __expf(-fabsf(x)));
}
__device__ __forceinline__ float logsig_f(float x) {
  return fminf(x, 0.f) - __logf(1.f + __expf(-fabsf(x)));
}
__device__ __forceinline__ short f2bf(float f) {   // RNE f32 -> bf16 bits
  uint32_t u = __builtin_bit_cast(uint32_t, f);
  u += 0x7FFFu + ((u >> 16) & 1u);
  return (short)(u >> 16);
}

#define WAITV(N) do { \
  asm volatile("s_waitcnt vmcnt(" #N ")" ::: "memory"); \
  __builtin_amdgcn_sched_barrier(0); \
} while (0)

#define DRAIN() do { \
  asm volatile("s_waitcnt vmcnt(0) lgkmcnt(0)" ::: "memory"); \
  __builtin_amdgcn_sched_barrier(0); \
} while (0)

#define SBAR() __builtin_amdgcn_sched_barrier(0)

// ---------- bf16-MFMA GEMM + activation + skew side store (both ops) -------
__global__ __launch_bounds__(256) void gemm_mfma(const float* __restrict__ ZX,
                                                 const float* __restrict__ ZY,
                                                 const float* __restrict__ GX,
                                                 const float* __restrict__ GY,
                                                 float* __restrict__ theta,
                                                 float* __restrict__ Amat,
                                                 float* __restrict__ thS,
                                                 float* __restrict__ aS) {
  const int z  = blockIdx.z;
  const int b  = z & 31;
  const int op = z >> 5;
  const int ty = blockIdx.y;
  const int tx = blockIdx.x;
  const float* Xb = (op ? GX : ZX) + (size_t)b * NN * DD;
  const float* Yb = (op ? GY : ZY) + (size_t)b * MM * DD;
  float* outb = (op ? Amat : theta) + (size_t)b * NN * MM;
  float* skb  = (op ? aS : thS) + (size_t)b * SPLN;

  __shared__ short xs[64][40];
  __shared__ short ys[64][40];

  const int tid = threadIdx.x;
  const int l   = tid & 63;
  const int w   = tid >> 6;
  const int r0  = (w >> 1) * 32;
  const int c0  = (w & 1) * 32;
  const int srow = tid >> 2;
  const int scg  = (tid & 3) * 8;

  f32x4_t acc[2][2];
  #pragma unroll
  for (int i = 0; i < 2; ++i)
    #pragma unroll
    for (int j = 0; j < 2; ++j) acc[i][j] = f32x4_t{0.f, 0.f, 0.f, 0.f};

  const int lr = l & 15;
  const int kof = (l >> 4) * 8;

  for (int ks = 0; ks < 16; ++ks) {
    const int k0 = ks * 32;
    const float4 xv0 = *(const float4*)(Xb + (size_t)(ty * 64 + srow) * DD + k0 + scg);
    const float4 xv1 = *(const float4*)(Xb + (size_t)(ty * 64 + srow) * DD + k0 + scg + 4);
    const float4 yv0 = *(const float4*)(Yb + (size_t)(tx * 64 + srow) * DD + k0 + scg);
    const float4 yv1 = *(const float4*)(Yb + (size_t)(tx * 64 + srow) * DD + k0 + scg + 4);
    __syncthreads();
    s16x8 xp, yp;
    xp[0] = f2bf(xv0.x); xp[1] = f2bf(xv0.y); xp[2] = f2bf(xv0.z); xp[3] = f2bf(xv0.w);
    xp[4] = f2bf(xv1.x); xp[5] = f2bf(xv1.y); xp[6] = f2bf(xv1.z); xp[7] = f2bf(xv1.w);
    yp[0] = f2bf(yv0.x); yp[1] = f2bf(yv0.y); yp[2] = f2bf(yv0.z); yp[3] = f2bf(yv0.w);
    yp[4] = f2bf(yv1.x); yp[5] = f2bf(yv1.y); yp[6] = f2bf(yv1.z); yp[7] = f2bf(yv1.w);
    *(s16x8*)&xs[srow][scg] = xp;
    *(s16x8*)&ys[srow][scg] = yp;
    __syncthreads();
    const s16x8 a0 = *(const s16x8*)&xs[r0 + lr][kof];
    const s16x8 a1 = *(const s16x8*)&xs[r0 + 16 + lr][kof];
    const s16x8 b0 = *(const s16x8*)&ys[c0 + lr][kof];
    const s16x8 b1 = *(const s16x8*)&ys[c0 + 16 + lr][kof];
    acc[0][0] = __builtin_amdgcn_mfma_f32_16x16x32_bf16(a0, b0, acc[0][0], 0, 0, 0);
    acc[0][1] = __builtin_amdgcn_mfma_f32_16x16x32_bf16(a0, b1, acc[0][1], 0, 0, 0);
    acc[1][0] = __builtin_amdgcn_mfma_f32_16x16x32_bf16(a1, b0, acc[1][0], 0, 0, 0);
    acc[1][1] = __builtin_amdgcn_mfma_f32_16x16x32_bf16(a1, b1, acc[1][1], 0, 0, 0);
  }

  #pragma unroll
  for (int i = 0; i < 2; ++i) {
    #pragma unroll
    for (int j = 0; j < 2; ++j) {
      #pragma unroll
      for (int r = 0; r < 4; ++r) {
        const int R = ty * 64 + r0 + i * 16 + (l >> 4) * 4 + r;
        const int C = tx * 64 + c0 + j * 16 + (l & 15);
        const float v = acc[i][j][r];
        const float act = (op == 0) ? softplus_f(v) : logsig_f(v);
        outb[(size_t)R * MM + C] = act;
        skb[(size_t)(C + 1 + (R >> 2)) * 256 + R] = act * LOG2E;
      }
    }
  }
}

// -------- wave-synchronous soft-NW, skewed, DS-pipelined -------------------
// One wave per batch; lane t owns grid rows 4t+1..4t+4, col j = m - t.
// All ds_read/shfl results are produced one step before use (latency hidden
// behind ~90 inst of compute); shfl count halved via the identities
// vd_in(m) = vu_in(m-1), sh_e2(u+1) = sh_e1(u), sh_q2(u+1) = sh_q1(u).
__global__ __launch_bounds__(64, 1) void nw_wave(const float* __restrict__ thSA,
                                                 const float* __restrict__ aSA,
                                                 u32x4_t* __restrict__ qSA,
                                                 float* __restrict__ eSA) {
  const int b = blockIdx.x;
  const int t = threadIdx.x;
  const float* thS = thSA + (size_t)b * SPLN;
  const float* aS  = aSA  + (size_t)b * SPLN;
  u32x4_t* qS = qSA + (size_t)b * (QPLN / 4);
  float* eSb = eSA + (size_t)b * EPLN;

  __shared__ f32x4_t stg[24][64];

  // ================= forward =================
  float vp[4];
  #pragma unroll
  for (int k = 0; k < 4; ++k) vp[k] = NEGF;
  float vu_sh = NEGF, vd_sh = NEGF;   // raw shfl pipeline regs

  auto fstage = [&](int rbase, int mlo) {
    #pragma unroll
    for (int q = 0; q < 4; ++q) {
      int m = mlo + q; m = m < 1 ? 1 : (m > 320 ? 320 : m);
      __builtin_amdgcn_global_load_lds((const void*)(thS + (size_t)m * 256 + 4 * t),
                                       (void*)&stg[rbase + q][0], 16, 0, 0);
      __builtin_amdgcn_global_load_lds((const void*)(aS + (size_t)m * 256 + 4 * t),
                                       (void*)&stg[rbase + 4 + q][0], 16, 0, 0);
    }
  };

  fstage(0, 1); fstage(8, 5); fstage(16, 9);
  u32x4_t* qpt = qS + 64 + t;   // plane m=1
  for (int h = 0; h < 80; ++h) {
    const int m0 = 1 + 4 * h;
    const int R = (h % 3) * 8;
    if (h == 0)      WAITV(16);
    else if (h == 1) WAITV(20);
    else             WAITV(24);
    f32x4_t thc = stg[R][t], ac = stg[R + 4][t];   // u=0 (exposed once/seg)
    f32x4_t thn, an;
    #pragma unroll
    for (int u = 0; u < 4; ++u) {
      if (u < 3) { thn = stg[R + u + 1][t]; an = stg[R + 4 + u + 1][t]; }
      SBAR();
      const int m = m0 + u;
      const int j = m - t;
      const bool actv = (j >= 1) && (j <= 256);
      float vu_in = vu_sh, vd_in = vd_sh;
      if (t == 0) { vu_in = NEGF; vd_in = (m == 1) ? 0.f : NEGF; }
      // off-chain: x2, partial max (ILP across cells)
      float x2v[4], m12[4];
      #pragma unroll
      for (int k = 0; k < 4; ++k) {
        x2v[k] = ac[k] + vp[k];
        const float vdk = (k == 0) ? vd_in : vp[k - 1];
        m12[k] = fmaxf(vdk, x2v[k]);
      }
      float vn[4];
      uint32_t pk[4];
      #pragma unroll
      for (int k = 0; k < 4; ++k) {
        const float vu  = (k == 0) ? vu_in : vn[k - 1];
        const float vdk = (k == 0) ? vd_in : vp[k - 1];
        const float x0 = ac[k] + vu;
        const float mx = fmaxf(x0, m12[k]);
        const float e0 = __builtin_amdgcn_exp2f(x0 - mx);
        const float e1 = __builtin_amdgcn_exp2f(vdk - mx);
        const float e2 = __builtin_amdgcn_exp2f(x2v[k] - mx);
        const float Z  = e0 + e1 + e2;
        const float rz = __builtin_amdgcn_rcpf(Z);
        const float v  = thc[k] + mx + __builtin_amdgcn_logf(Z);  // log2
        vn[k] = actv ? v : vp[k];
        pk[k] = pack_q(e0 * rz, e2 * rz);   // (q1,q3); q2 = 1-q1-q3
      }
      qpt[0] = u32x4_t{pk[0], pk[1], pk[2], pk[3]};
      qpt += 64;
      // pipeline: one shfl for next step; vd chain is last step's vu (raw)
      const float nsh = __shfl_up(vn[3], 1);
      vd_sh = vu_sh; vu_sh = nsh;
      #pragma unroll
      for (int k = 0; k < 4; ++k) vp[k] = vn[k];
      if (u < 3) { thc = thn; ac = an; }
    }
    fstage(R, m0 + 12);
  }

  DRAIN();  // qS RAW boundary (fwd stores -> bwd staged reads)

  // ================= backward =================
  float ep[4] = {0.f, 0.f, 0.f, 0.f};
  float sh_e1 = 0.f, sh_e2 = 0.f;
  uint32_t sh_q1 = 0u, sh_q2 = 0u;
  u32x4_t qm1 = u32x4_t{0u, 0u, 0u, 0u};
  const u32x4_t QONE = u32x4_t{0x3C00u, 0x3C00u, 0x3C00u, 0x3C00u};

  auto bstage = [&](int rbase, int Phi) {
    #pragma unroll
    for (int u = 0; u < 4; ++u) {
      int P = Phi - u; P = P < 0 ? 0 : (P > 320 ? 320 : P);
      __builtin_amdgcn_global_load_lds((const void*)(qS + (size_t)P * 64 + t),
                                       (void*)&stg[rbase + u][0], 16, 0, 0);
    }
  };

  bstage(0, 319); bstage(4, 315); bstage(8, 311);
  float* eptr = eSb + 4 * t;
  for (int n = 0; n < 80; ++n) {
    const int R = (n % 3) * 4;
    if (n == 0)      WAITV(8);
    else if (n == 1) WAITV(12);
    else             WAITV(16);
    u32x4_t cur = __builtin_bit_cast(u32x4_t, stg[R][t]);
    u32x4_t nxt;
    #pragma unroll
    for (int u = 0; u < 4; ++u) {
      if (u < 3) nxt = __builtin_bit_cast(u32x4_t, stg[R + u + 1][t]);
      SBAR();
      const int mp = 4 * n + u;
      const int P  = 319 - mp;
      const int j  = P - t;
      const bool actv = (j >= 1) && (j <= 256);
      const bool jok  = (j <= 255);
      // hoisted masks: j-mask folds into qm1 (0x3C00 => q2d=0, q3l=0);
      // i-mask (i=256 only at lane63 k=3) folds into the shfl'd words.
      const u32x4_t qmm = jok ? qm1 : QONE;
      const uint32_t sq1 = (t == 63) ? 0u : sh_q1;
      const uint32_t sq2 = (t == 63 || !jok) ? 0x3C00u : sh_q2;
      float en[4];
      #pragma unroll
      for (int kk = 0; kk < 4; ++kk) {
        const int k = 3 - kk;
        const uint32_t uA = (k < 3) ? cur[k + 1] : sq1;   // Q1 of (i+1, j)
        const uint32_t uB = (k < 3) ? qmm[k + 1] : sq2;   // Q of (i+1, j+1)
        const uint32_t uC = qmm[k];                       // Q3 of (i, j+1)
        const float2 fA = unpack_q(uA);
        const float2 fB = unpack_q(uB);
        const float2 fC = unpack_q(uC);
        const float q1u = fA.x;
        const float q2d = 1.f - fB.x - fB.y;
        const float q3l = fC.y;
        const float eu = (k < 3) ? en[k + 1] : sh_e1;
        const float ed = (k < 3) ? ep[k + 1] : sh_e2;
        const float el = ep[k];
        float E = q1u * eu + q2d * ed + q3l * el;
        if (n == 0 && u == 0 && k == 3) E = (t == 63) ? 1.f : E;  // seed
        en[k] = actv ? E : 0.f;
      }
      *(f32x4_t*)eptr = f32x4_t{en[0], en[1], en[2], en[3]};
      eptr += 256;
      // pipeline shfls for next step (identities halve the count)
      const float ne = __shfl_down(en[0], 1);
      sh_e2 = sh_e1; sh_e1 = ne;
      const uint32_t nq = (uint32_t)__shfl_down((int)cur[0], 1);
      sh_q2 = sh_q1; sh_q1 = nq;
      ep[0] = en[0]; ep[1] = en[1]; ep[2] = en[2]; ep[3] = en[3];
      qm1 = cur;
      if (u < 3) cur = nxt;
    }
    bstage(R, 307 - 4 * n);
  }
}

// -------- skew-layout E -> row-major aln (tiled LDS transpose) --------
__global__ __launch_bounds__(256) void untwist(const float* __restrict__ eS,
                                               float* __restrict__ aln) {
  const int b  = blockIdx.z;
  const int r0 = blockIdx.y * 64;
  const int c0 = blockIdx.x * 64;
  const int tid = threadIdx.x;
  const float* ep = eS + (size_t)b * EPLN;

  __shared__ float ld[80][65];

  const int lx = tid & 63;
  const int wy = tid >> 6;
  const int mbase = 240 - c0 - (r0 >> 2);
  #pragma unroll
  for (int k = 0; k < 20; ++k) {
    const int p = wy + 4 * k;
    ld[p][lx] = ep[(size_t)(mbase + p) * 256 + r0 + lx];
  }
  __syncthreads();
  #pragma unroll
  for (int k = 0; k < 16; ++k) {
    const int rr = wy + 4 * k;
    aln[(size_t)b * NN * MM + (size_t)(r0 + rr) * MM + c0 + lx] =
        ld[78 - lx - (rr >> 2)][rr];
  }
}

// ---------------- launcher ----------------
extern "C" void kernel_launch(void* const* d_in, const int* in_sizes, int n_in,
                              void* d_out, int out_size, void* d_ws, size_t ws_size,
                              hipStream_t stream) {
  const float* zx = (const float*)d_in[0];
  const float* zy = (const float*)d_in[1];
  const float* gx = (const float*)d_in[2];
  const float* gy = (const float*)d_in[3];

  float* out   = (float*)d_out;
  float* aln   = out;                              // [B][N][M]
  float* theta = out + (size_t)BB * NN * MM;       // [B][N][M]
  float* Amat  = out + (size_t)2 * BB * NN * MM;   // [B][N][M]

  float* ws  = (float*)d_ws;
  float* thS = ws;                                   // [B][321][256] f32
  float* aS  = ws + (size_t)BB * SPLN;               // [B][321][256] f32
  u32x4_t* qS = (u32x4_t*)(ws + (size_t)2 * BB * SPLN);  // [B][321][64] u32x4
  float* eS = ws + (size_t)3 * BB * SPLN;            // [B][320][256] f32

  gemm_mfma<<<dim3(4, 4, 64), 256, 0, stream>>>(zx, zy, gx, gy,
                                                theta, Amat, thS, aS);
  nw_wave<<<BB, 64, 0, stream>>>(thS, aS, qS, eS);
  untwist<<<dim3(4, 4, BB), 256, 0, stream>>>(eS, aln);
}